// Round 2
// baseline (1635.478 us; speedup 1.0000x reference)
//
#include <hip/hip_runtime.h>
#include <hip/hip_bf16.h>

#define BB 16
#define TT 1024
#define CC 2048
#define MM (BB*TT)   // 16384 rows total

typedef __attribute__((ext_vector_type(4))) float f32x4;
typedef __attribute__((ext_vector_type(8))) short bf16x8;

__device__ __forceinline__ unsigned short f2bf(float f) {
  union { float f; unsigned u; } x; x.f = f;
  unsigned r = x.u + 0x7fffu + ((x.u >> 16) & 1u);
  return (unsigned short)(r >> 16);
}
__device__ __forceinline__ float bf2f(unsigned short u) {
  union { unsigned u; float f; } x; x.u = ((unsigned)u) << 16;
  return x.f;
}

__device__ __forceinline__ ushort4 mix4(float4 a, float4 b, float4 m) {
  ushort4 o;
  o.x = f2bf(a.x * m.x + b.x * (1.f - m.x));
  o.y = f2bf(a.y * m.y + b.y * (1.f - m.y));
  o.z = f2bf(a.z * m.z + b.z * (1.f - m.z));
  o.w = f2bf(a.w * m.w + b.w * (1.f - m.w));
  return o;
}

// fp32 -> bf16 (4-wide), grid-stride
__global__ void f2bf_kernel(const float* __restrict__ in,
                            unsigned short* __restrict__ out, int n4) {
  for (int i = blockIdx.x * blockDim.x + threadIdx.x; i < n4;
       i += gridDim.x * blockDim.x) {
    float4 v = ((const float4*)in)[i];
    ushort4 o;
    o.x = f2bf(v.x); o.y = f2bf(v.y); o.z = f2bf(v.z); o.w = f2bf(v.w);
    ((ushort4*)out)[i] = o;
  }
}

// time-shift mix for a T-chunk [t0, t0+Tc): writes chunk-local [16][Tc][C] bf16
__global__ void mix_kernel(const float* __restrict__ x,
                           const float* __restrict__ tmk,
                           const float* __restrict__ tmv,
                           const float* __restrict__ tmr,
                           unsigned short* __restrict__ xk,
                           unsigned short* __restrict__ xv,
                           unsigned short* __restrict__ xr,
                           int t0, int Tc) {
  const int C4 = CC / 4;
  const int total = BB * Tc * C4;
  for (int g = blockIdx.x * blockDim.x + threadIdx.x; g < total;
       g += gridDim.x * blockDim.x) {
    int cg = g % C4;
    int lrow = g / C4;          // local row: b*Tc + tl
    int tl = lrow % Tc;
    int b = lrow / Tc;
    int t = t0 + tl;            // global timestep
    size_t gidx = (size_t)(b * TT + t) * C4 + cg;
    float4 xc = ((const float4*)x)[gidx];
    float4 xp = make_float4(0.f, 0.f, 0.f, 0.f);
    if (t > 0) xp = ((const float4*)x)[gidx - C4];
    ((ushort4*)xk)[g] = mix4(xc, xp, ((const float4*)tmk)[cg]);
    ((ushort4*)xv)[g] = mix4(xc, xp, ((const float4*)tmv)[cg]);
    ((ushort4*)xr)[g] = mix4(xc, xp, ((const float4*)tmr)[cg]);
  }
}

// C[orow,N] = A[M,K] * B[N,K]^T ; A,B bf16 (K contiguous).
// m97 structure: 128x128 tile, BK=32, 4 waves (2x2), 16x16x32 MFMA, acc[4][4].
// Output row remap: orow = (r>>tcShift)*1024 + t0 + (r & ((1<<tcShift)-1)).
// (tcShift=10, t0=0 is the identity for local writes since TT=1024.)
template<bool BF16OUT>
__global__ __launch_bounds__(256)
void gemm_bt(const unsigned short* __restrict__ A,
             const unsigned short* __restrict__ B,
             void* __restrict__ Cv, int M, int N, int K, int tcShift, int t0) {
  __shared__ __align__(16) unsigned short lA[128 * 32];
  __shared__ __align__(16) unsigned short lB[128 * 32];
  const int tid = threadIdx.x;
  const int wave = tid >> 6;
  const int lane = tid & 63;
  const int wr = wave >> 1, wc = wave & 1;
  const int row0 = blockIdx.x * 128;
  const int col0 = blockIdx.y * 128;

  const int srow = tid >> 2;         // 0..63
  const int scol = (tid & 3) << 3;   // 0,8,16,24
  const unsigned short* gA0 = A + (size_t)(row0 + srow) * K + scol;
  const unsigned short* gA1 = A + (size_t)(row0 + 64 + srow) * K + scol;
  const unsigned short* gB0 = B + (size_t)(col0 + srow) * K + scol;
  const unsigned short* gB1 = B + (size_t)(col0 + 64 + srow) * K + scol;

  f32x4 acc[4][4] = {};

  const int frow = lane & 15;
  const int fk = (lane >> 4) << 3;

  for (int k0 = 0; k0 < K; k0 += 32) {
    __builtin_amdgcn_global_load_lds(
        (const __attribute__((address_space(1))) void*)(gA0 + k0),
        (__attribute__((address_space(3))) void*)(lA + wave * 512), 16, 0, 0);
    __builtin_amdgcn_global_load_lds(
        (const __attribute__((address_space(1))) void*)(gA1 + k0),
        (__attribute__((address_space(3))) void*)(lA + 2048 + wave * 512), 16, 0, 0);
    __builtin_amdgcn_global_load_lds(
        (const __attribute__((address_space(1))) void*)(gB0 + k0),
        (__attribute__((address_space(3))) void*)(lB + wave * 512), 16, 0, 0);
    __builtin_amdgcn_global_load_lds(
        (const __attribute__((address_space(1))) void*)(gB1 + k0),
        (__attribute__((address_space(3))) void*)(lB + 2048 + wave * 512), 16, 0, 0);
    __syncthreads();

    bf16x8 af[4], bfr[4];
#pragma unroll
    for (int m = 0; m < 4; ++m)
      af[m] = *(const bf16x8*)(lA + (wr * 64 + m * 16 + frow) * 32 + fk);
#pragma unroll
    for (int n = 0; n < 4; ++n)
      bfr[n] = *(const bf16x8*)(lB + (wc * 64 + n * 16 + frow) * 32 + fk);
#pragma unroll
    for (int m = 0; m < 4; ++m)
#pragma unroll
      for (int n = 0; n < 4; ++n)
        acc[m][n] = __builtin_amdgcn_mfma_f32_16x16x32_bf16(af[m], bfr[n],
                                                            acc[m][n], 0, 0, 0);
    __syncthreads();
  }

  // C/D layout: col = lane&15, row = (lane>>4)*4 + reg  [m89-verified]
  const int crow = (lane >> 4) * 4;
  const int ccol = lane & 15;
  const int tcMask = (1 << tcShift) - 1;
#pragma unroll
  for (int m = 0; m < 4; ++m)
#pragma unroll
    for (int n = 0; n < 4; ++n) {
      const int col = col0 + wc * 64 + n * 16 + ccol;
#pragma unroll
      for (int j = 0; j < 4; ++j) {
        int r = row0 + wr * 64 + m * 16 + crow + j;
        int orow = ((r >> tcShift) << 10) + t0 + (r & tcMask);
        if (BF16OUT)
          ((unsigned short*)Cv)[(size_t)orow * N + col] = f2bf(acc[m][n][j]);
        else
          ((float*)Cv)[(size_t)orow * N + col] = acc[m][n][j];
      }
    }
}

// WKV recurrence for a T-chunk; one thread per (b, c). fp32 state carried in ws.
__global__ void wkv_kernel(const float* __restrict__ time_decay,
                           const float* __restrict__ time_first,
                           const float* __restrict__ k,
                           const float* __restrict__ v,
                           const unsigned short* __restrict__ r,
                           unsigned short* __restrict__ rwkv,
                           float* __restrict__ state,   // [3][BB*CC]
                           int t0, int Tc) {
  int idx = blockIdx.x * blockDim.x + threadIdx.x;  // [0, BB*CC)
  int b = idx >> 11, c = idx & (CC - 1);
  float w = -__expf(time_decay[c]);
  float u = time_first[c];
  float aa, bb, pp;
  if (t0 == 0) { aa = 0.f; bb = 0.f; pp = -1e38f; }
  else {
    aa = state[idx];
    bb = state[BB * CC + idx];
    pp = state[2 * BB * CC + idx];
  }
  size_t base = (size_t)b * Tc * CC + c;
  for (int t = 0; t < Tc; ++t) {
    size_t off = base + (size_t)t * CC;
    float kt = k[off], vt = v[off];
    float ww = u + kt;
    float p = fmaxf(pp, ww);
    float e1 = __expf(pp - p), e2 = __expf(ww - p);
    float y = (e1 * aa + e2 * vt) / (e1 * bb + e2);
    float rr = bf2f(r[off]);
    float sr = 1.f / (1.f + __expf(-rr));
    rwkv[off] = f2bf(sr * y);
    float ww2 = pp + w;
    float p2 = fmaxf(ww2, kt);
    float e1b = __expf(ww2 - p2), e2b = __expf(kt - p2);
    aa = e1b * aa + e2b * vt;
    bb = e1b * bb + e2b;
    pp = p2;
  }
  state[idx] = aa;
  state[BB * CC + idx] = bb;
  state[2 * BB * CC + idx] = pp;
}

extern "C" void kernel_launch(void* const* d_in, const int* in_sizes, int n_in,
                              void* d_out, int out_size, void* d_ws,
                              size_t ws_size, hipStream_t stream) {
  const float* x          = (const float*)d_in[0];
  const float* time_decay = (const float*)d_in[1];
  const float* time_first = (const float*)d_in[2];
  const float* tmk        = (const float*)d_in[3];
  const float* tmv        = (const float*)d_in[4];
  const float* tmr        = (const float*)d_in[5];
  const float* key_w      = (const float*)d_in[6];
  const float* value_w    = (const float*)d_in[7];
  const float* rec_w      = (const float*)d_in[8];
  const float* out_w      = (const float*)d_in[9];
  float* out = (float*)d_out;

  const size_t WW = (size_t)CC * CC;          // weight elements
  const size_t wtBytes = 4 * WW * 2;          // 32 MB (4 bf16 weights)
  const size_t stBytes = 3 * (size_t)BB * CC * 4;  // 384 KB state

  // pick largest T-chunk that fits:
  // per-chunk = BB*Tc*CC * (xk2 + xv2 + xr2 + rbuf2 + kbuf4 + vbuf4) bytes
  int Tc = 1024;
  while (Tc > 32) {
    size_t chunkBytes = (size_t)BB * Tc * CC * 16;
    if (wtBytes + stBytes + chunkBytes + 1024 <= ws_size) break;
    Tc >>= 1;
  }
  const int Mc = BB * Tc;                     // rows per chunk
  const size_t NC = (size_t)Mc * CC;          // chunk elements

  char* p = (char*)d_ws;
  unsigned short* wk  = (unsigned short*)p; p += WW * 2;
  unsigned short* wv  = (unsigned short*)p; p += WW * 2;
  unsigned short* wrr = (unsigned short*)p; p += WW * 2;
  unsigned short* wo  = (unsigned short*)p; p += WW * 2;
  float* state        = (float*)p;          p += stBytes;
  float* kbuf         = (float*)p;          p += NC * 4;
  float* vbuf         = (float*)p;          p += NC * 4;
  unsigned short* xk  = (unsigned short*)p; p += NC * 2;  // aliased: rwkv
  unsigned short* xv  = (unsigned short*)p; p += NC * 2;
  unsigned short* xr  = (unsigned short*)p; p += NC * 2;
  unsigned short* rbuf= (unsigned short*)p; p += NC * 2;
  unsigned short* rwkv = xk;  // xk dead after the k-GEMM

  f2bf_kernel<<<1024, 256, 0, stream>>>(key_w, wk, (int)(WW / 4));
  f2bf_kernel<<<1024, 256, 0, stream>>>(value_w, wv, (int)(WW / 4));
  f2bf_kernel<<<1024, 256, 0, stream>>>(rec_w, wrr, (int)(WW / 4));
  f2bf_kernel<<<1024, 256, 0, stream>>>(out_w, wo, (int)(WW / 4));

  int tcShift = 0;
  while ((1 << tcShift) < Tc) ++tcShift;

  dim3 grid(Mc / 128, CC / 128);
  int mixBlocks = (Mc * (CC / 4) + 255) / 256;
  if (mixBlocks > 4096) mixBlocks = 4096;

  for (int t0 = 0; t0 < TT; t0 += Tc) {
    mix_kernel<<<mixBlocks, 256, 0, stream>>>(x, tmk, tmv, tmr, xk, xv, xr,
                                              t0, Tc);
    // local writes: tcShift=10,t0=0 is identity (TT=1024)
    gemm_bt<false><<<grid, 256, 0, stream>>>(xk, wk, kbuf, Mc, CC, CC, 10, 0);
    gemm_bt<false><<<grid, 256, 0, stream>>>(xv, wv, vbuf, Mc, CC, CC, 10, 0);
    gemm_bt<true><<<grid, 256, 0, stream>>>(xr, wrr, rbuf, Mc, CC, CC, 10, 0);
    wkv_kernel<<<(BB * CC) / 256, 256, 0, stream>>>(time_decay, time_first,
                                                    kbuf, vbuf, rbuf, rwkv,
                                                    state, t0, Tc);
    // global scatter back to [B, T] rows
    gemm_bt<false><<<grid, 256, 0, stream>>>(rwkv, wo, out, Mc, CC, CC,
                                             tcShift, t0);
  }
}

// Round 3
// 753.341 us; speedup vs baseline: 2.1710x; 2.1710x over previous
//
#include <hip/hip_runtime.h>
#include <hip/hip_bf16.h>

#define BB 16
#define TT 1024
#define CC 2048
#define TS 32   // wkv scan segment length

typedef __attribute__((ext_vector_type(4))) float f32x4;
typedef __attribute__((ext_vector_type(8))) short bf16x8;

__device__ __forceinline__ unsigned short f2bf(float f) {
  union { float f; unsigned u; } x; x.f = f;
  unsigned r = x.u + 0x7fffu + ((x.u >> 16) & 1u);
  return (unsigned short)(r >> 16);
}
__device__ __forceinline__ float bf2f(unsigned short u) {
  union { unsigned u; float f; } x; x.u = ((unsigned)u) << 16;
  return x.f;
}

__device__ __forceinline__ ushort4 mix4(float4 a, float4 b, float4 m) {
  ushort4 o;
  o.x = f2bf(a.x * m.x + b.x * (1.f - m.x));
  o.y = f2bf(a.y * m.y + b.y * (1.f - m.y));
  o.z = f2bf(a.z * m.z + b.z * (1.f - m.z));
  o.w = f2bf(a.w * m.w + b.w * (1.f - m.w));
  return o;
}

__global__ void f2bf_kernel(const float* __restrict__ in,
                            unsigned short* __restrict__ out, int n4) {
  for (int i = blockIdx.x * blockDim.x + threadIdx.x; i < n4;
       i += gridDim.x * blockDim.x) {
    float4 v = ((const float4*)in)[i];
    ushort4 o;
    o.x = f2bf(v.x); o.y = f2bf(v.y); o.z = f2bf(v.z); o.w = f2bf(v.w);
    ((ushort4*)out)[i] = o;
  }
}

__global__ void mix_kernel(const float* __restrict__ x,
                           const float* __restrict__ tmk,
                           const float* __restrict__ tmv,
                           const float* __restrict__ tmr,
                           unsigned short* __restrict__ xk,
                           unsigned short* __restrict__ xv,
                           unsigned short* __restrict__ xr,
                           int t0, int Tc) {
  const int C4 = CC / 4;
  const int total = BB * Tc * C4;
  for (int g = blockIdx.x * blockDim.x + threadIdx.x; g < total;
       g += gridDim.x * blockDim.x) {
    int cg = g % C4;
    int lrow = g / C4;
    int tl = lrow % Tc;
    int b = lrow / Tc;
    int t = t0 + tl;
    size_t gidx = (size_t)(b * TT + t) * C4 + cg;
    float4 xc = ((const float4*)x)[gidx];
    float4 xp = make_float4(0.f, 0.f, 0.f, 0.f);
    if (t > 0) xp = ((const float4*)x)[gidx - C4];
    ((ushort4*)xk)[g] = mix4(xc, xp, ((const float4*)tmk)[cg]);
    ((ushort4*)xv)[g] = mix4(xc, xp, ((const float4*)tmv)[cg]);
    ((ushort4*)xr)[g] = mix4(xc, xp, ((const float4*)tmr)[cg]);
  }
}

// ---------------------------------------------------------------------------
// 256x256 GEMM, BK=64, 8 waves (2x4), double-buffered 128KB LDS,
// counted-vmcnt 4-phase schedule (never drains to 0 in steady state),
// LDS swizzle colByte ^= (row&7)<<4 (pre-swizzled global source + swizzled read).
// C[orow,N] = A[M,K] * B[N,K]^T. orow = (r>>tcShift)<<10 + t0 + (r & mask).
// ---------------------------------------------------------------------------
template<bool BF16OUT>
__global__ __launch_bounds__(512, 2)
void gemm256(const unsigned short* __restrict__ A,
             const unsigned short* __restrict__ B,
             void* __restrict__ Cv, int M, int N, int K,
             int tcShift, int t0) {
  __shared__ __align__(1024) unsigned char lds[131072];
  const int tid = threadIdx.x;
  const int lane = tid & 63;
  const int wid = tid >> 6;
  const int wr = wid >> 2;   // 0..1
  const int wc = wid & 3;    // 0..3

  // XCD-aware bijective swizzle (nwg % 8 == 0 always here)
  const int nwg = gridDim.x;
  const int cpx = nwg >> 3;
  const int bid = blockIdx.x;
  const int wg = (bid & 7) * cpx + (bid >> 3);
  const int bcolN = N >> 8;
  const int brow = wg / bcolN;
  const int bcol = wg % bcolN;

  const unsigned short* Ag = A + (size_t)(brow * 256) * K;
  const unsigned short* Bg = B + (size_t)(bcol * 256) * K;

  // staging geometry: one round = 64 rows x 64 cols = 8KB = 512 thr x 16B
  const int srow = tid >> 3;                                  // 0..63
  const int scolB = ((tid & 7) * 16) ^ ((srow & 7) << 4);     // swizzled src byte
  const int scolE = scolB >> 1;
  const int ldsWave = wid * 1024;

#define STAGE(gbase, rowOff, ldsOff, kOff)                                     \
  __builtin_amdgcn_global_load_lds(                                            \
      (const __attribute__((address_space(1))) void*)(                         \
          (gbase) + (size_t)((rowOff) + srow) * K + (kOff) + scolE),           \
      (__attribute__((address_space(3))) void*)(lds + (ldsOff) + ldsWave),     \
      16, 0, 0)

  const int frow = lane & 15;
  const int fhi = (lane >> 4) << 4;   // byte offset of lane's 8-elem group

#define FRAG(tb, row, kk)                                                      \
  (*(const bf16x8*)(lds + (tb) + (row) * 128 +                                 \
                    ((((kk) << 6) + fhi) ^ (((row) & 7) << 4))))

  const int NT = K >> 6;

  // Prologue: K-tile 0 into buf0. Order: B0a,B0b,B1a,B1b,Aq0,Aq2,Aq1,Aq3
  STAGE(Bg,   0, 32768 +     0, 0);
  STAGE(Bg,  64, 32768 +  8192, 0);
  STAGE(Bg, 128, 32768 + 16384, 0);
  STAGE(Bg, 192, 32768 + 24576, 0);
  STAGE(Ag,   0,             0, 0);
  STAGE(Ag, 128,         16384, 0);
  STAGE(Ag,  64,          8192, 0);
  STAGE(Ag, 192,         24576, 0);

  f32x4 acc[8][4] = {};
  bf16x8 af[8], bfr[8];

  for (int kt = 0; kt < NT; ++kt) {
    const int p = kt & 1;
    const int Ab = p * 65536;
    const int Bb = Ab + 32768;
    const int An = (p ^ 1) * 65536;
    const int Bn = An + 32768;
    const int kN = (kt + 1) << 6;
    const bool st = (kt + 1 < NT);

    // top wait: B(kt), A-q0/q2(kt) guaranteed; A-q1/q3(kt) may be in flight
    asm volatile("s_waitcnt vmcnt(2)" ::: "memory");
    __builtin_amdgcn_s_barrier();

    // ph0: stage next-B rows 0-127; read A(m0-3)+B(n0-1); mfma q(mh0,nh0)
    if (st) { STAGE(Bg, 0, Bn, kN); STAGE(Bg, 64, Bn + 8192, kN); }
#pragma unroll
    for (int m = 0; m < 4; ++m)
#pragma unroll
      for (int kk = 0; kk < 2; ++kk)
        af[m * 2 + kk] = FRAG(Ab, wr * 128 + m * 16 + frow, kk);
#pragma unroll
    for (int n = 0; n < 2; ++n)
#pragma unroll
      for (int kk = 0; kk < 2; ++kk)
        bfr[n * 2 + kk] = FRAG(Bb, wc * 64 + n * 16 + frow, kk);
    __builtin_amdgcn_s_setprio(1);
#pragma unroll
    for (int m = 0; m < 4; ++m)
#pragma unroll
      for (int n = 0; n < 2; ++n)
#pragma unroll
        for (int kk = 0; kk < 2; ++kk)
          acc[m][n] = __builtin_amdgcn_mfma_f32_16x16x32_bf16(
              af[m * 2 + kk], bfr[n * 2 + kk], acc[m][n], 0, 0, 0);
    __builtin_amdgcn_s_setprio(0);
    __builtin_amdgcn_s_barrier();

    // ph1: stage next-B rows 128-255; read B(n2-3); mfma q(mh0,nh1)
    if (st) { STAGE(Bg, 128, Bn + 16384, kN); STAGE(Bg, 192, Bn + 24576, kN); }
#pragma unroll
    for (int n = 2; n < 4; ++n)
#pragma unroll
      for (int kk = 0; kk < 2; ++kk)
        bfr[n * 2 + kk] = FRAG(Bb, wc * 64 + n * 16 + frow, kk);
    __builtin_amdgcn_s_setprio(1);
#pragma unroll
    for (int m = 0; m < 4; ++m)
#pragma unroll
      for (int n = 2; n < 4; ++n)
#pragma unroll
        for (int kk = 0; kk < 2; ++kk)
          acc[m][n] = __builtin_amdgcn_mfma_f32_16x16x32_bf16(
              af[m * 2 + kk], bfr[n * 2 + kk], acc[m][n], 0, 0, 0);
    __builtin_amdgcn_s_setprio(0);

    // mid wait: A-q1/q3(kt) guaranteed (newest 4 = next-B stages)
    if (st) { asm volatile("s_waitcnt vmcnt(4)" ::: "memory"); }
    else    { asm volatile("s_waitcnt vmcnt(0)" ::: "memory"); }
    __builtin_amdgcn_s_barrier();

    // ph2: stage next-A q0,q2; read A(m4-7); mfma q(mh1,nh1)
    if (st) { STAGE(Ag, 0, An, kN); STAGE(Ag, 128, An + 16384, kN); }
#pragma unroll
    for (int m = 0; m < 4; ++m)
#pragma unroll
      for (int kk = 0; kk < 2; ++kk)
        af[m * 2 + kk] = FRAG(Ab, wr * 128 + 64 + m * 16 + frow, kk);
    __builtin_amdgcn_s_setprio(1);
#pragma unroll
    for (int m = 0; m < 4; ++m)
#pragma unroll
      for (int n = 2; n < 4; ++n)
#pragma unroll
        for (int kk = 0; kk < 2; ++kk)
          acc[4 + m][n] = __builtin_amdgcn_mfma_f32_16x16x32_bf16(
              af[m * 2 + kk], bfr[n * 2 + kk], acc[4 + m][n], 0, 0, 0);
    __builtin_amdgcn_s_setprio(0);
    __builtin_amdgcn_s_barrier();

    // ph3: stage next-A q1,q3; mfma q(mh1,nh0)
    if (st) { STAGE(Ag, 64, An + 8192, kN); STAGE(Ag, 192, An + 24576, kN); }
    __builtin_amdgcn_s_setprio(1);
#pragma unroll
    for (int m = 0; m < 4; ++m)
#pragma unroll
      for (int n = 0; n < 2; ++n)
#pragma unroll
        for (int kk = 0; kk < 2; ++kk)
          acc[4 + m][n] = __builtin_amdgcn_mfma_f32_16x16x32_bf16(
              af[m * 2 + kk], bfr[n * 2 + kk], acc[4 + m][n], 0, 0, 0);
    __builtin_amdgcn_s_setprio(0);
    // loop top does vmcnt+barrier
  }
#undef STAGE
#undef FRAG

  const int crow0 = (lane >> 4) << 2;
  const int ccol = lane & 15;
  const int tcMask = (1 << tcShift) - 1;
#pragma unroll
  for (int m = 0; m < 8; ++m)
#pragma unroll
    for (int n = 0; n < 4; ++n) {
      const int col = bcol * 256 + wc * 64 + n * 16 + ccol;
#pragma unroll
      for (int j = 0; j < 4; ++j) {
        int r = brow * 256 + wr * 128 + m * 16 + crow0 + j;
        int orow = ((r >> tcShift) << 10) + t0 + (r & tcMask);
        if (BF16OUT)
          ((unsigned short*)Cv)[(size_t)orow * N + col] = f2bf(acc[m][n][j]);
        else
          ((float*)Cv)[(size_t)orow * N + col] = acc[m][n][j];
      }
    }
}

// ---------------------------------------------------------------------------
// WKV segmented scan. Segment = TS steps. a,b state is affine per step:
// a' = e^w a + e^{k_t} v_t, so over a segment: out = e^{w*TS}*in + partial.
// Stabilized rep (aa,bb,pp): a = aa*e^pp.
// ---------------------------------------------------------------------------
__global__ void wkv_part(const float* __restrict__ time_decay,
                         const float* __restrict__ k,
                         const float* __restrict__ v,
                         float* __restrict__ paA, float* __restrict__ paB,
                         float* __restrict__ paP, int Tc) {
  int idx = blockIdx.x * blockDim.x + threadIdx.x;  // [0, S*BB*CC)
  int c = idx & (CC - 1);
  int b = (idx >> 11) & (BB - 1);
  int s = idx >> 15;
  float w = -__expf(time_decay[c]);
  float aa = 0.f, bb = 0.f, pp = -1e38f;
  size_t base = ((size_t)b * Tc + s * TS) * CC + c;
  for (int t = 0; t < TS; ++t) {
    float kt = k[base + (size_t)t * CC], vt = v[base + (size_t)t * CC];
    float ww2 = pp + w;
    float p2 = fmaxf(ww2, kt);
    float e1 = __expf(ww2 - p2), e2 = __expf(kt - p2);
    aa = e1 * aa + e2 * vt;
    bb = e1 * bb + e2;
    pp = p2;
  }
  paA[idx] = aa; paB[idx] = bb; paP[idx] = pp;
}

__global__ void wkv_comb(const float* __restrict__ time_decay,
                         const float* __restrict__ paA,
                         const float* __restrict__ paB,
                         const float* __restrict__ paP,
                         float* __restrict__ inA, float* __restrict__ inB,
                         float* __restrict__ inP,
                         float* __restrict__ state, int S, int t0) {
  int idx = blockIdx.x * blockDim.x + threadIdx.x;  // [0, BB*CC)
  int c = idx & (CC - 1);
  float w = -__expf(time_decay[c]);
  float wTs = w * (float)TS;
  float A, Bv, P;
  if (t0 == 0) { A = 0.f; Bv = 0.f; P = -1e38f; }
  else { A = state[idx]; Bv = state[32768 + idx]; P = state[65536 + idx]; }
  for (int s = 0; s < S; ++s) {
    size_t o = (size_t)s * 32768 + idx;
    inA[o] = A; inB[o] = Bv; inP[o] = P;
    float Pd = P + wTs;
    float Ps = paP[o];
    float Pn = fmaxf(Pd, Ps);
    float e1 = __expf(Pd - Pn), e2 = __expf(Ps - Pn);
    A = e1 * A + e2 * paA[o];
    Bv = e1 * Bv + e2 * paB[o];
    P = Pn;
  }
  state[idx] = A; state[32768 + idx] = Bv; state[65536 + idx] = P;
}

__global__ void wkv_out(const float* __restrict__ time_decay,
                        const float* __restrict__ time_first,
                        const float* __restrict__ k,
                        const float* __restrict__ v,
                        const unsigned short* __restrict__ r,
                        unsigned short* __restrict__ rwkv,
                        const float* __restrict__ inA,
                        const float* __restrict__ inB,
                        const float* __restrict__ inP, int Tc) {
  int idx = blockIdx.x * blockDim.x + threadIdx.x;
  int c = idx & (CC - 1);
  int b = (idx >> 11) & (BB - 1);
  int s = idx >> 15;
  float w = -__expf(time_decay[c]);
  float u = time_first[c];
  float aa = inA[idx], bb = inB[idx], pp = inP[idx];
  size_t base = ((size_t)b * Tc + s * TS) * CC + c;
  for (int t = 0; t < TS; ++t) {
    size_t off = base + (size_t)t * CC;
    float kt = k[off], vt = v[off];
    float ww = u + kt;
    float p = fmaxf(pp, ww);
    float e1 = __expf(pp - p), e2 = __expf(ww - p);
    float y = (e1 * aa + e2 * vt) / (e1 * bb + e2);
    float rr = bf2f(r[off]);
    float sr = 1.f / (1.f + __expf(-rr));
    rwkv[off] = f2bf(sr * y);
    float ww2 = pp + w;
    float p2 = fmaxf(ww2, kt);
    float e1b = __expf(ww2 - p2), e2b = __expf(kt - p2);
    aa = e1b * aa + e2b * vt;
    bb = e1b * bb + e2b;
    pp = p2;
  }
}

extern "C" void kernel_launch(void* const* d_in, const int* in_sizes, int n_in,
                              void* d_out, int out_size, void* d_ws,
                              size_t ws_size, hipStream_t stream) {
  const float* x          = (const float*)d_in[0];
  const float* time_decay = (const float*)d_in[1];
  const float* time_first = (const float*)d_in[2];
  const float* tmk        = (const float*)d_in[3];
  const float* tmv        = (const float*)d_in[4];
  const float* tmr        = (const float*)d_in[5];
  const float* key_w      = (const float*)d_in[6];
  const float* value_w    = (const float*)d_in[7];
  const float* rec_w      = (const float*)d_in[8];
  const float* out_w      = (const float*)d_in[9];
  float* out = (float*)d_out;

  const size_t WW = (size_t)CC * CC;
  const size_t wtBytes = 4 * WW * 2;               // 32 MB
  const size_t stBytes = 3 * (size_t)BB * CC * 4;  // 384 KB

  int Tc = 1024;
  while (Tc > 32) {
    size_t chunkBytes = (size_t)BB * Tc * CC * 16;
    if (wtBytes + stBytes + chunkBytes + 1024 <= ws_size) break;
    Tc >>= 1;
  }
  const int Mc = BB * Tc;
  const size_t NC = (size_t)Mc * CC;
  const int S = Tc / TS;

  char* p = (char*)d_ws;
  unsigned short* wk  = (unsigned short*)p; p += WW * 2;
  unsigned short* wv  = (unsigned short*)p; p += WW * 2;
  unsigned short* wrr = (unsigned short*)p; p += WW * 2;
  unsigned short* wo  = (unsigned short*)p; p += WW * 2;
  float* state        = (float*)p;          p += stBytes;
  float* kbuf         = (float*)p;          p += NC * 4;
  float* vbuf         = (float*)p;          p += NC * 4;
  unsigned short* xk  = (unsigned short*)p; p += NC * 2;  // aliased: rwkv
  unsigned short* xv  = (unsigned short*)p; p += NC * 2;  // aliased: scan bufs
  unsigned short* xr  = (unsigned short*)p; p += NC * 2;
  unsigned short* rbuf= (unsigned short*)p; p += NC * 2;
  unsigned short* rwkv = xk;

  // scan buffers overlay xv (dead after v-GEMM): 6*S*32768*4 <= NC*2 always
  const size_t SBt = (size_t)S * 32768;
  float* paA = (float*)xv;
  float* paB = paA + SBt;
  float* paP = paB + SBt;
  float* inA = paP + SBt;
  float* inB = inA + SBt;
  float* inP = inB + SBt;

  f2bf_kernel<<<1024, 256, 0, stream>>>(key_w, wk, (int)(WW / 4));
  f2bf_kernel<<<1024, 256, 0, stream>>>(value_w, wv, (int)(WW / 4));
  f2bf_kernel<<<1024, 256, 0, stream>>>(rec_w, wrr, (int)(WW / 4));
  f2bf_kernel<<<1024, 256, 0, stream>>>(out_w, wo, (int)(WW / 4));

  int tcShift = 0;
  while ((1 << tcShift) < Tc) ++tcShift;

  const int nwg = (Mc / 256) * (CC / 256);
  int mixBlocks = (Mc * (CC / 4) + 255) / 256;
  if (mixBlocks > 4096) mixBlocks = 4096;

  for (int t0 = 0; t0 < TT; t0 += Tc) {
    mix_kernel<<<mixBlocks, 256, 0, stream>>>(x, tmk, tmv, tmr, xk, xv, xr,
                                              t0, Tc);
    gemm256<false><<<nwg, 512, 0, stream>>>(xk, wk, kbuf, Mc, CC, CC, 10, 0);
    gemm256<false><<<nwg, 512, 0, stream>>>(xv, wv, vbuf, Mc, CC, CC, 10, 0);
    gemm256<true><<<nwg, 512, 0, stream>>>(xr, wrr, rbuf, Mc, CC, CC, 10, 0);

    wkv_part<<<S * 128, 256, 0, stream>>>(time_decay, kbuf, vbuf,
                                          paA, paB, paP, Tc);
    wkv_comb<<<128, 256, 0, stream>>>(time_decay, paA, paB, paP,
                                      inA, inB, inP, state, S, t0);
    wkv_out<<<S * 128, 256, 0, stream>>>(time_decay, time_first, kbuf, vbuf,
                                         rbuf, rwkv, inA, inB, inP, Tc);

    gemm256<false><<<nwg, 512, 0, stream>>>(rwkv, wo, out, Mc, CC, CC,
                                            tcShift, t0);
  }
}

// Round 4
// 740.072 us; speedup vs baseline: 2.2099x; 1.0179x over previous
//
#include <hip/hip_runtime.h>
#include <hip/hip_bf16.h>

#define BB 16
#define TT 1024
#define CC 2048
#define TS 32   // wkv scan segment length

typedef __attribute__((ext_vector_type(4))) float f32x4;
typedef __attribute__((ext_vector_type(8))) short bf16x8;

__device__ __forceinline__ unsigned short f2bf(float f) {
  union { float f; unsigned u; } x; x.f = f;
  unsigned r = x.u + 0x7fffu + ((x.u >> 16) & 1u);
  return (unsigned short)(r >> 16);
}
__device__ __forceinline__ float bf2f(unsigned short u) {
  union { unsigned u; float f; } x; x.u = ((unsigned)u) << 16;
  return x.f;
}

__device__ __forceinline__ ushort4 mix4(float4 a, float4 b, float4 m) {
  ushort4 o;
  o.x = f2bf(a.x * m.x + b.x * (1.f - m.x));
  o.y = f2bf(a.y * m.y + b.y * (1.f - m.y));
  o.z = f2bf(a.z * m.z + b.z * (1.f - m.z));
  o.w = f2bf(a.w * m.w + b.w * (1.f - m.w));
  return o;
}

// all 4 weight matrices fp32 -> bf16 in one dispatch
__global__ void f2bf_all(const float* __restrict__ w0, const float* __restrict__ w1,
                         const float* __restrict__ w2, const float* __restrict__ w3,
                         unsigned short* __restrict__ o0, unsigned short* __restrict__ o1,
                         unsigned short* __restrict__ o2, unsigned short* __restrict__ o3,
                         int n4each) {
  const float* ws[4] = {w0, w1, w2, w3};
  unsigned short* os[4] = {o0, o1, o2, o3};
  int total = 4 * n4each;
  for (int i = blockIdx.x * blockDim.x + threadIdx.x; i < total;
       i += gridDim.x * blockDim.x) {
    int seg = i / n4each, j = i - seg * n4each;
    float4 v = ((const float4*)ws[seg])[j];
    ushort4 o;
    o.x = f2bf(v.x); o.y = f2bf(v.y); o.z = f2bf(v.z); o.w = f2bf(v.w);
    ((ushort4*)os[seg])[j] = o;
  }
}

__global__ void mix_kernel(const float* __restrict__ x,
                           const float* __restrict__ tmk,
                           const float* __restrict__ tmv,
                           const float* __restrict__ tmr,
                           unsigned short* __restrict__ xk,
                           unsigned short* __restrict__ xv,
                           unsigned short* __restrict__ xr,
                           int t0, int Tc) {
  const int C4 = CC / 4;
  const int total = BB * Tc * C4;
  for (int g = blockIdx.x * blockDim.x + threadIdx.x; g < total;
       g += gridDim.x * blockDim.x) {
    int cg = g % C4;
    int lrow = g / C4;
    int tl = lrow % Tc;
    int b = lrow / Tc;
    int t = t0 + tl;
    size_t gidx = (size_t)(b * TT + t) * C4 + cg;
    float4 xc = ((const float4*)x)[gidx];
    float4 xp = make_float4(0.f, 0.f, 0.f, 0.f);
    if (t > 0) xp = ((const float4*)x)[gidx - C4];
    ((ushort4*)xk)[g] = mix4(xc, xp, ((const float4*)tmk)[cg]);
    ((ushort4*)xv)[g] = mix4(xc, xp, ((const float4*)tmv)[cg]);
    ((ushort4*)xr)[g] = mix4(xc, xp, ((const float4*)tmr)[cg]);
  }
}

// ---------------------------------------------------------------------------
// 256x256 GEMM, BK=64, 8 waves (2x4), double-buffered 128KB LDS,
// counted-vmcnt 4-phase schedule, st-swizzled LDS (both-sides, rule #21),
// XCD-bijective block swizzle. C[orow,N] = A[M,K]*B[N,K]^T.
// orow = (r>>tcShift)<<10 + t0 + (r & mask)  (tcShift=10,t0=0 => identity).
// ---------------------------------------------------------------------------
template<bool BF16OUT>
__global__ __launch_bounds__(512, 2)
void gemm256(const unsigned short* __restrict__ A,
             const unsigned short* __restrict__ B,
             void* __restrict__ Cv, int M, int N, int K,
             int tcShift, int t0) {
  __shared__ __align__(1024) unsigned char lds[131072];
  const int tid = threadIdx.x;
  const int lane = tid & 63;
  const int wid = tid >> 6;
  const int wr = wid >> 2;   // 0..1
  const int wc = wid & 3;    // 0..3

  const int nwg = gridDim.x;
  const int cpx = nwg >> 3;
  const int bid = blockIdx.x;
  const int wg = (bid & 7) * cpx + (bid >> 3);
  const int bcolN = N >> 8;
  const int brow = wg / bcolN;
  const int bcol = wg % bcolN;

  const unsigned short* Ag = A + (size_t)(brow * 256) * K;
  const unsigned short* Bg = B + (size_t)(bcol * 256) * K;

  const int srow = tid >> 3;                                  // 0..63
  const int scolB = ((tid & 7) * 16) ^ ((srow & 7) << 4);     // pre-swizzled src
  const int scolE = scolB >> 1;
  const int ldsWave = wid * 1024;

#define STAGE(gbase, rowOff, ldsOff, kOff)                                     \
  __builtin_amdgcn_global_load_lds(                                            \
      (const __attribute__((address_space(1))) void*)(                         \
          (gbase) + (size_t)((rowOff) + srow) * K + (kOff) + scolE),           \
      (__attribute__((address_space(3))) void*)(lds + (ldsOff) + ldsWave),     \
      16, 0, 0)

  const int frow = lane & 15;
  const int fhi = (lane >> 4) << 4;

#define FRAG(tb, row, kk)                                                      \
  (*(const bf16x8*)(lds + (tb) + (row) * 128 +                                 \
                    ((((kk) << 6) + fhi) ^ (((row) & 7) << 4))))

  const int NT = K >> 6;

  STAGE(Bg,   0, 32768 +     0, 0);
  STAGE(Bg,  64, 32768 +  8192, 0);
  STAGE(Bg, 128, 32768 + 16384, 0);
  STAGE(Bg, 192, 32768 + 24576, 0);
  STAGE(Ag,   0,             0, 0);
  STAGE(Ag, 128,         16384, 0);
  STAGE(Ag,  64,          8192, 0);
  STAGE(Ag, 192,         24576, 0);

  f32x4 acc[8][4] = {};
  bf16x8 af[8], bfr[8];

  for (int kt = 0; kt < NT; ++kt) {
    const int p = kt & 1;
    const int Ab = p * 65536;
    const int Bb = Ab + 32768;
    const int An = (p ^ 1) * 65536;
    const int Bn = An + 32768;
    const int kN = (kt + 1) << 6;
    const bool st = (kt + 1 < NT);

    asm volatile("s_waitcnt vmcnt(2)" ::: "memory");
    __builtin_amdgcn_s_barrier();

    // ph0
    if (st) { STAGE(Bg, 0, Bn, kN); STAGE(Bg, 64, Bn + 8192, kN); }
#pragma unroll
    for (int m = 0; m < 4; ++m)
#pragma unroll
      for (int kk = 0; kk < 2; ++kk)
        af[m * 2 + kk] = FRAG(Ab, wr * 128 + m * 16 + frow, kk);
#pragma unroll
    for (int n = 0; n < 2; ++n)
#pragma unroll
      for (int kk = 0; kk < 2; ++kk)
        bfr[n * 2 + kk] = FRAG(Bb, wc * 64 + n * 16 + frow, kk);
    __builtin_amdgcn_s_setprio(1);
#pragma unroll
    for (int m = 0; m < 4; ++m)
#pragma unroll
      for (int n = 0; n < 2; ++n)
#pragma unroll
        for (int kk = 0; kk < 2; ++kk)
          acc[m][n] = __builtin_amdgcn_mfma_f32_16x16x32_bf16(
              af[m * 2 + kk], bfr[n * 2 + kk], acc[m][n], 0, 0, 0);
    __builtin_amdgcn_s_setprio(0);
    __builtin_amdgcn_s_barrier();

    // ph1
    if (st) { STAGE(Bg, 128, Bn + 16384, kN); STAGE(Bg, 192, Bn + 24576, kN); }
#pragma unroll
    for (int n = 2; n < 4; ++n)
#pragma unroll
      for (int kk = 0; kk < 2; ++kk)
        bfr[n * 2 + kk] = FRAG(Bb, wc * 64 + n * 16 + frow, kk);
    __builtin_amdgcn_s_setprio(1);
#pragma unroll
    for (int m = 0; m < 4; ++m)
#pragma unroll
      for (int n = 2; n < 4; ++n)
#pragma unroll
        for (int kk = 0; kk < 2; ++kk)
          acc[m][n] = __builtin_amdgcn_mfma_f32_16x16x32_bf16(
              af[m * 2 + kk], bfr[n * 2 + kk], acc[m][n], 0, 0, 0);
    __builtin_amdgcn_s_setprio(0);

    if (st) { asm volatile("s_waitcnt vmcnt(4)" ::: "memory"); }
    else    { asm volatile("s_waitcnt vmcnt(0)" ::: "memory"); }
    __builtin_amdgcn_s_barrier();

    // ph2
    if (st) { STAGE(Ag, 0, An, kN); STAGE(Ag, 128, An + 16384, kN); }
#pragma unroll
    for (int m = 0; m < 4; ++m)
#pragma unroll
      for (int kk = 0; kk < 2; ++kk)
        af[m * 2 + kk] = FRAG(Ab, wr * 128 + 64 + m * 16 + frow, kk);
    __builtin_amdgcn_s_setprio(1);
#pragma unroll
    for (int m = 0; m < 4; ++m)
#pragma unroll
      for (int n = 2; n < 4; ++n)
#pragma unroll
        for (int kk = 0; kk < 2; ++kk)
          acc[4 + m][n] = __builtin_amdgcn_mfma_f32_16x16x32_bf16(
              af[m * 2 + kk], bfr[n * 2 + kk], acc[4 + m][n], 0, 0, 0);
    __builtin_amdgcn_s_setprio(0);
    __builtin_amdgcn_s_barrier();

    // ph3
    if (st) { STAGE(Ag, 64, An + 8192, kN); STAGE(Ag, 192, An + 24576, kN); }
    __builtin_amdgcn_s_setprio(1);
#pragma unroll
    for (int m = 0; m < 4; ++m)
#pragma unroll
      for (int n = 0; n < 2; ++n)
#pragma unroll
        for (int kk = 0; kk < 2; ++kk)
          acc[4 + m][n] = __builtin_amdgcn_mfma_f32_16x16x32_bf16(
              af[m * 2 + kk], bfr[n * 2 + kk], acc[4 + m][n], 0, 0, 0);
    __builtin_amdgcn_s_setprio(0);
  }
#undef STAGE
#undef FRAG

  const int crow0 = (lane >> 4) << 2;
  const int ccol = lane & 15;
  const int tcMask = (1 << tcShift) - 1;
#pragma unroll
  for (int m = 0; m < 8; ++m)
#pragma unroll
    for (int n = 0; n < 4; ++n) {
      const int col = bcol * 256 + wc * 64 + n * 16 + ccol;
#pragma unroll
      for (int j = 0; j < 4; ++j) {
        int r = brow * 256 + wr * 128 + m * 16 + crow0 + j;
        int orow = ((r >> tcShift) << 10) + t0 + (r & tcMask);
        if (BF16OUT)
          ((unsigned short*)Cv)[(size_t)orow * N + col] = f2bf(acc[m][n][j]);
        else
          ((float*)Cv)[(size_t)orow * N + col] = acc[m][n][j];
      }
    }
}

// ---------------------------------------------------------------------------
// WKV segmented scan (segment = TS steps), stabilized (aa,bb,pp) form.
// k fp32 (feeds exp), v bf16 (linear).
// ---------------------------------------------------------------------------
__global__ void wkv_part(const float* __restrict__ time_decay,
                         const float* __restrict__ k,
                         const unsigned short* __restrict__ v,
                         float* __restrict__ paA, float* __restrict__ paB,
                         float* __restrict__ paP, int Tc) {
  int idx = blockIdx.x * blockDim.x + threadIdx.x;
  int c = idx & (CC - 1);
  int b = (idx >> 11) & (BB - 1);
  int s = idx >> 15;
  float w = -__expf(time_decay[c]);
  float aa = 0.f, bb = 0.f, pp = -1e38f;
  size_t base = ((size_t)b * Tc + s * TS) * CC + c;
  for (int t = 0; t < TS; ++t) {
    size_t off = base + (size_t)t * CC;
    float kt = k[off], vt = bf2f(v[off]);
    float ww2 = pp + w;
    float p2 = fmaxf(ww2, kt);
    float e1 = __expf(ww2 - p2), e2 = __expf(kt - p2);
    aa = e1 * aa + e2 * vt;
    bb = e1 * bb + e2;
    pp = p2;
  }
  paA[idx] = aa; paB[idx] = bb; paP[idx] = pp;
}

__global__ void wkv_comb(const float* __restrict__ time_decay,
                         const float* __restrict__ paA,
                         const float* __restrict__ paB,
                         const float* __restrict__ paP,
                         float* __restrict__ inA, float* __restrict__ inB,
                         float* __restrict__ inP,
                         float* __restrict__ state, int S, int t0) {
  int idx = blockIdx.x * blockDim.x + threadIdx.x;  // [0, BB*CC)
  int c = idx & (CC - 1);
  float w = -__expf(time_decay[c]);
  float wTs = w * (float)TS;
  float A, Bv, P;
  if (t0 == 0) { A = 0.f; Bv = 0.f; P = -1e38f; }
  else { A = state[idx]; Bv = state[32768 + idx]; P = state[65536 + idx]; }
  for (int s = 0; s < S; ++s) {
    size_t o = (size_t)s * 32768 + idx;
    inA[o] = A; inB[o] = Bv; inP[o] = P;
    float Pd = P + wTs;
    float Ps = paP[o];
    float Pn = fmaxf(Pd, Ps);
    float e1 = __expf(Pd - Pn), e2 = __expf(Ps - Pn);
    A = e1 * A + e2 * paA[o];
    Bv = e1 * Bv + e2 * paB[o];
    P = Pn;
  }
  state[idx] = A; state[32768 + idx] = Bv; state[65536 + idx] = P;
}

__global__ void wkv_out(const float* __restrict__ time_decay,
                        const float* __restrict__ time_first,
                        const float* __restrict__ k,
                        const unsigned short* __restrict__ v,
                        const unsigned short* __restrict__ r,
                        unsigned short* __restrict__ rwkv,
                        const float* __restrict__ inA,
                        const float* __restrict__ inB,
                        const float* __restrict__ inP, int Tc) {
  int idx = blockIdx.x * blockDim.x + threadIdx.x;
  int c = idx & (CC - 1);
  int b = (idx >> 11) & (BB - 1);
  int s = idx >> 15;
  float w = -__expf(time_decay[c]);
  float u = time_first[c];
  float aa = inA[idx], bb = inB[idx], pp = inP[idx];
  size_t base = ((size_t)b * Tc + s * TS) * CC + c;
  for (int t = 0; t < TS; ++t) {
    size_t off = base + (size_t)t * CC;
    float kt = k[off], vt = bf2f(v[off]);
    float ww = u + kt;
    float p = fmaxf(pp, ww);
    float e1 = __expf(pp - p), e2 = __expf(ww - p);
    float y = (e1 * aa + e2 * vt) / (e1 * bb + e2);
    float rr = bf2f(r[off]);
    float sr = 1.f / (1.f + __expf(-rr));
    rwkv[off] = f2bf(sr * y);
    float ww2 = pp + w;
    float p2 = fmaxf(ww2, kt);
    float e1b = __expf(ww2 - p2), e2b = __expf(kt - p2);
    aa = e1b * aa + e2b * vt;
    bb = e1b * bb + e2b;
    pp = p2;
  }
}

extern "C" void kernel_launch(void* const* d_in, const int* in_sizes, int n_in,
                              void* d_out, int out_size, void* d_ws,
                              size_t ws_size, hipStream_t stream) {
  const float* x          = (const float*)d_in[0];
  const float* time_decay = (const float*)d_in[1];
  const float* time_first = (const float*)d_in[2];
  const float* tmk        = (const float*)d_in[3];
  const float* tmv        = (const float*)d_in[4];
  const float* tmr        = (const float*)d_in[5];
  const float* key_w      = (const float*)d_in[6];
  const float* value_w    = (const float*)d_in[7];
  const float* rec_w      = (const float*)d_in[8];
  const float* out_w      = (const float*)d_in[9];
  float* out = (float*)d_out;

  const size_t WW = (size_t)CC * CC;
  const size_t wtBytes = 4 * WW * 2;               // 32 MB
  const size_t stBytes = 3 * (size_t)BB * CC * 4;  // 384 KB

  // per-chunk = BB*Tc*CC * (xk2 + xv2 + xr2 + rbuf2 + kbuf4 + vbuf2) = 14 B/elem
  int Tc = 1024;
  while (Tc > 32) {
    size_t chunkBytes = (size_t)BB * Tc * CC * 14;
    if (wtBytes + stBytes + chunkBytes + 1024 <= ws_size) break;
    Tc >>= 1;
  }
  const int Mc = BB * Tc;
  const size_t NC = (size_t)Mc * CC;
  const int S = Tc / TS;

  char* p = (char*)d_ws;
  unsigned short* wk  = (unsigned short*)p; p += WW * 2;
  unsigned short* wv  = (unsigned short*)p; p += WW * 2;
  unsigned short* wrr = (unsigned short*)p; p += WW * 2;
  unsigned short* wo  = (unsigned short*)p; p += WW * 2;
  float* state        = (float*)p;          p += stBytes;
  float* kbuf         = (float*)p;          p += NC * 4;
  unsigned short* vbuf= (unsigned short*)p; p += NC * 2;
  unsigned short* xk  = (unsigned short*)p; p += NC * 2;  // aliased: rwkv
  unsigned short* xv  = (unsigned short*)p; p += NC * 2;  // aliased: scan bufs
  unsigned short* xr  = (unsigned short*)p; p += NC * 2;
  unsigned short* rbuf= (unsigned short*)p; p += NC * 2;
  unsigned short* rwkv = xk;

  // scan buffers overlay xv (dead after v-GEMM): 6*S*32768*4 <= NC*2 always
  const size_t SBt = (size_t)S * 32768;
  float* paA = (float*)xv;
  float* paB = paA + SBt;
  float* paP = paB + SBt;
  float* inA = paP + SBt;
  float* inB = inA + SBt;
  float* inP = inB + SBt;

  f2bf_all<<<2048, 256, 0, stream>>>(key_w, value_w, rec_w, out_w,
                                     wk, wv, wrr, wo, (int)(WW / 4));

  int tcShift = 0;
  while ((1 << tcShift) < Tc) ++tcShift;

  const int nwg = (Mc / 256) * (CC / 256);
  int mixBlocks = (Mc * (CC / 4) + 255) / 256;
  if (mixBlocks > 4096) mixBlocks = 4096;

  for (int t0 = 0; t0 < TT; t0 += Tc) {
    mix_kernel<<<mixBlocks, 256, 0, stream>>>(x, tmk, tmv, tmr, xk, xv, xr,
                                              t0, Tc);
    gemm256<false><<<nwg, 512, 0, stream>>>(xk, wk, kbuf, Mc, CC, CC, 10, 0);
    gemm256<true><<<nwg, 512, 0, stream>>>(xv, wv, vbuf, Mc, CC, CC, 10, 0);
    // wkv_part right after v-GEMM: kbuf+vbuf (192MB) still L3-hot
    wkv_part<<<S * 128, 256, 0, stream>>>(time_decay, kbuf, vbuf,
                                          paA, paB, paP, Tc);
    gemm256<true><<<nwg, 512, 0, stream>>>(xr, wrr, rbuf, Mc, CC, CC, 10, 0);
    wkv_comb<<<128, 256, 0, stream>>>(time_decay, paA, paB, paP,
                                      inA, inB, inP, state, S, t0);
    wkv_out<<<S * 128, 256, 0, stream>>>(time_decay, time_first, kbuf, vbuf,
                                         rbuf, rwkv, inA, inB, inP, Tc);
    gemm256<false><<<nwg, 512, 0, stream>>>(rwkv, wo, out, Mc, CC, CC,
                                            tcShift, t0);
  }
}

// Round 5
// 728.104 us; speedup vs baseline: 2.2462x; 1.0164x over previous
//
#include <hip/hip_runtime.h>
#include <hip/hip_bf16.h>

#define BB 16
#define TT 1024
#define CC 2048
#define TS 32   // wkv scan segment length

typedef __attribute__((ext_vector_type(4))) float f32x4;
typedef __attribute__((ext_vector_type(8))) short bf16x8;

__device__ __forceinline__ unsigned short f2bf(float f) {
  union { float f; unsigned u; } x; x.f = f;
  unsigned r = x.u + 0x7fffu + ((x.u >> 16) & 1u);
  return (unsigned short)(r >> 16);
}
__device__ __forceinline__ float bf2f(unsigned short u) {
  union { unsigned u; float f; } x; x.u = ((unsigned)u) << 16;
  return x.f;
}

__device__ __forceinline__ ushort4 mix4(float4 a, float4 b, float4 m) {
  ushort4 o;
  o.x = f2bf(a.x * m.x + b.x * (1.f - m.x));
  o.y = f2bf(a.y * m.y + b.y * (1.f - m.y));
  o.z = f2bf(a.z * m.z + b.z * (1.f - m.z));
  o.w = f2bf(a.w * m.w + b.w * (1.f - m.w));
  return o;
}

__global__ void f2bf_all(const float* __restrict__ w0, const float* __restrict__ w1,
                         const float* __restrict__ w2, const float* __restrict__ w3,
                         unsigned short* __restrict__ o0, unsigned short* __restrict__ o1,
                         unsigned short* __restrict__ o2, unsigned short* __restrict__ o3,
                         int n4each) {
  const float* ws[4] = {w0, w1, w2, w3};
  unsigned short* os[4] = {o0, o1, o2, o3};
  int total = 4 * n4each;
  for (int i = blockIdx.x * blockDim.x + threadIdx.x; i < total;
       i += gridDim.x * blockDim.x) {
    int seg = i / n4each, j = i - seg * n4each;
    float4 v = ((const float4*)ws[seg])[j];
    ushort4 o;
    o.x = f2bf(v.x); o.y = f2bf(v.y); o.z = f2bf(v.z); o.w = f2bf(v.w);
    ((ushort4*)os[seg])[j] = o;
  }
}

__global__ void mix_kernel(const float* __restrict__ x,
                           const float* __restrict__ tmk,
                           const float* __restrict__ tmv,
                           const float* __restrict__ tmr,
                           unsigned short* __restrict__ xk,
                           unsigned short* __restrict__ xv,
                           unsigned short* __restrict__ xr,
                           int t0, int Tc) {
  const int C4 = CC / 4;
  const int total = BB * Tc * C4;
  for (int g = blockIdx.x * blockDim.x + threadIdx.x; g < total;
       g += gridDim.x * blockDim.x) {
    int cg = g % C4;
    int lrow = g / C4;
    int tl = lrow % Tc;
    int b = lrow / Tc;
    int t = t0 + tl;
    size_t gidx = (size_t)(b * TT + t) * C4 + cg;
    float4 xc = ((const float4*)x)[gidx];
    float4 xp = make_float4(0.f, 0.f, 0.f, 0.f);
    if (t > 0) xp = ((const float4*)x)[gidx - C4];
    ((ushort4*)xk)[g] = mix4(xc, xp, ((const float4*)tmk)[cg]);
    ((ushort4*)xv)[g] = mix4(xc, xp, ((const float4*)tmv)[cg]);
    ((ushort4*)xr)[g] = mix4(xc, xp, ((const float4*)tmr)[cg]);
  }
}

// ---------------------------------------------------------------------------
// 256x256 GEMM, BK=64, 8 waves (2x4), double-buffered 128KB LDS,
// issue-early/consume-late 4-block schedule, counted vmcnt (never 0 in loop),
// st-swizzled LDS both-sides, XCD-bijective block swizzle.
// C[orow,N] = A[M,K]*B[N,K]^T ; orow = (r>>tcShift)<<10 + t0 + (r&mask).
// ---------------------------------------------------------------------------
template<bool BF16OUT>
__global__ __launch_bounds__(512, 2)
void gemm256(const unsigned short* __restrict__ A,
             const unsigned short* __restrict__ B,
             void* __restrict__ Cv, int M, int N, int K,
             int tcShift, int t0) {
  __shared__ __align__(1024) unsigned char lds[131072];
  const int tid = threadIdx.x;
  const int lane = tid & 63;
  const int wid = tid >> 6;
  const int wr = wid >> 2;   // 0..1
  const int wc = wid & 3;    // 0..3

  const int nwg = gridDim.x;
  const int cpx = nwg >> 3;
  const int bid = blockIdx.x;
  const int wg = (bid & 7) * cpx + (bid >> 3);
  const int bcolN = N >> 8;
  const int brow = wg / bcolN;
  const int bcol = wg % bcolN;

  const unsigned short* Ag = A + (size_t)(brow * 256) * K;
  const unsigned short* Bg = B + (size_t)(bcol * 256) * K;

  const int srow = tid >> 3;                                  // 0..63
  const int scolB = ((tid & 7) * 16) ^ ((srow & 7) << 4);     // pre-swizzled src
  const int scolE = scolB >> 1;
  const int ldsWave = wid * 1024;

#define STAGE(gbase, rowOff, ldsOff, kOff)                                     \
  __builtin_amdgcn_global_load_lds(                                            \
      (const __attribute__((address_space(1))) void*)(                         \
          (gbase) + (size_t)((rowOff) + srow) * K + (kOff) + scolE),           \
      (__attribute__((address_space(3))) void*)(lds + (ldsOff) + ldsWave),     \
      16, 0, 0)

  const int frow = lane & 15;
  const int fhi = (lane >> 4) << 4;

#define FRAG(tb, row, kk)                                                      \
  (*(const bf16x8*)(lds + (tb) + (row) * 128 +                                 \
                    ((((kk) << 6) + fhi) ^ (((row) & 7) << 4))))

#define FENCE asm volatile("" ::: "memory")

  const int NT = K >> 6;

  // Prologue: stage K-tile 0 into buf0, order B01,B23,A02,A13.
  STAGE(Bg,   0, 32768 +     0, 0);
  STAGE(Bg,  64, 32768 +  8192, 0);
  STAGE(Bg, 128, 32768 + 16384, 0);
  STAGE(Bg, 192, 32768 + 24576, 0);
  STAGE(Ag,   0,             0, 0);
  STAGE(Ag, 128,         16384, 0);
  STAGE(Ag,  64,          8192, 0);
  STAGE(Ag, 192,         24576, 0);

  f32x4 acc[8][4] = {};
  bf16x8 af0[8], af1[8], bf0[4], bf1[4];

  // wait B01,B23,A02 of kt0 (A13 stays in flight); then first reads
  asm volatile("s_waitcnt vmcnt(2)" ::: "memory");
  __builtin_amdgcn_s_barrier();
#pragma unroll
  for (int m = 0; m < 4; ++m)
#pragma unroll
    for (int kk = 0; kk < 2; ++kk)
      af0[m * 2 + kk] = FRAG(0, wr * 128 + m * 16 + frow, kk);
#pragma unroll
  for (int n = 0; n < 2; ++n)
#pragma unroll
    for (int kk = 0; kk < 2; ++kk)
      bf0[n * 2 + kk] = FRAG(32768, wc * 64 + n * 16 + frow, kk);

  for (int kt = 0; kt < NT; ++kt) {
    const int cur = (kt & 1) << 16;          // A tile base; B = +32768
    const int nxt = ((kt + 1) & 1) << 16;
    const int kN = (kt + 1) << 6;
    const bool st = (kt + 1 < NT);

    // ---- blk0: q00 = af0 x bf0 ----
    if (st) { STAGE(Bg, 0, nxt + 32768, kN); STAGE(Bg, 64, nxt + 32768 + 8192, kN); }
    __builtin_amdgcn_s_setprio(1);
#pragma unroll
    for (int m = 0; m < 4; ++m)
#pragma unroll
      for (int n = 0; n < 2; ++n)
#pragma unroll
        for (int kk = 0; kk < 2; ++kk)
          acc[m][n] = __builtin_amdgcn_mfma_f32_16x16x32_bf16(
              af0[m * 2 + kk], bf0[n * 2 + kk], acc[m][n], 0, 0, 0);
    __builtin_amdgcn_s_setprio(0);
    // read bf1 (cur; B rows long since resident)
#pragma unroll
    for (int n = 0; n < 2; ++n)
#pragma unroll
      for (int kk = 0; kk < 2; ++kk)
        bf1[n * 2 + kk] = FRAG(cur + 32768, wc * 64 + 32 + n * 16 + frow, kk);
    FENCE;
    // drain A13(kt) so af1 reads are safe after the barrier
    if (st) { asm volatile("s_waitcnt vmcnt(2)" ::: "memory"); }
    else    { asm volatile("s_waitcnt vmcnt(0)" ::: "memory"); }
    __builtin_amdgcn_s_barrier();

    // ---- blk1: q01 = af0 x bf1 ----
    if (st) { STAGE(Bg, 128, nxt + 32768 + 16384, kN); STAGE(Bg, 192, nxt + 32768 + 24576, kN); }
    // read af1 early (consumed in blk2)
#pragma unroll
    for (int m = 0; m < 4; ++m)
#pragma unroll
      for (int kk = 0; kk < 2; ++kk)
        af1[m * 2 + kk] = FRAG(cur, wr * 128 + 64 + m * 16 + frow, kk);
    __builtin_amdgcn_s_setprio(1);
#pragma unroll
    for (int m = 0; m < 4; ++m)
#pragma unroll
      for (int n = 0; n < 2; ++n)
#pragma unroll
        for (int kk = 0; kk < 2; ++kk)
          acc[m][2 + n] = __builtin_amdgcn_mfma_f32_16x16x32_bf16(
              af0[m * 2 + kk], bf1[n * 2 + kk], acc[m][2 + n], 0, 0, 0);
    __builtin_amdgcn_s_setprio(0);
    FENCE;
    __builtin_amdgcn_s_barrier();

    // ---- blk2: q11 = af1 x bf1 ----
    if (st) { STAGE(Ag, 0, nxt, kN); STAGE(Ag, 128, nxt + 16384, kN); }
    __builtin_amdgcn_s_setprio(1);
#pragma unroll
    for (int m = 0; m < 4; ++m)
#pragma unroll
      for (int n = 0; n < 2; ++n)
#pragma unroll
        for (int kk = 0; kk < 2; ++kk)
          acc[4 + m][2 + n] = __builtin_amdgcn_mfma_f32_16x16x32_bf16(
              af1[m * 2 + kk], bf1[n * 2 + kk], acc[4 + m][2 + n], 0, 0, 0);
    __builtin_amdgcn_s_setprio(0);
    FENCE;
    __builtin_amdgcn_s_barrier();

    // ---- blk3: q10 = af1 x bf0 ----
    if (st) { STAGE(Ag, 64, nxt + 8192, kN); STAGE(Ag, 192, nxt + 24576, kN); }
    __builtin_amdgcn_s_setprio(1);
#pragma unroll
    for (int m = 0; m < 4; ++m)
#pragma unroll
      for (int n = 0; n < 2; ++n)
#pragma unroll
        for (int kk = 0; kk < 2; ++kk)
          acc[4 + m][n] = __builtin_amdgcn_mfma_f32_16x16x32_bf16(
              af1[m * 2 + kk], bf0[n * 2 + kk], acc[4 + m][n], 0, 0, 0);
    __builtin_amdgcn_s_setprio(0);
    if (st) {
      // drain B01,B23,A02 of kt+1 (A13 of kt+1 stays in flight), then
      // read next af0/bf0 behind the barrier
      asm volatile("s_waitcnt vmcnt(2)" ::: "memory");
      __builtin_amdgcn_s_barrier();
#pragma unroll
      for (int m = 0; m < 4; ++m)
#pragma unroll
        for (int kk = 0; kk < 2; ++kk)
          af0[m * 2 + kk] = FRAG(nxt, wr * 128 + m * 16 + frow, kk);
#pragma unroll
      for (int n = 0; n < 2; ++n)
#pragma unroll
        for (int kk = 0; kk < 2; ++kk)
          bf0[n * 2 + kk] = FRAG(nxt + 32768, wc * 64 + n * 16 + frow, kk);
      FENCE;
    }
  }
#undef STAGE
#undef FRAG
#undef FENCE

  const int crow0 = (lane >> 4) << 2;
  const int ccol = lane & 15;
  const int tcMask = (1 << tcShift) - 1;
#pragma unroll
  for (int am = 0; am < 8; ++am)
#pragma unroll
    for (int an = 0; an < 4; ++an) {
      const int col = bcol * 256 + wc * 64 + (an >> 1) * 32 + (an & 1) * 16 + ccol;
#pragma unroll
      for (int j = 0; j < 4; ++j) {
        int r = brow * 256 + wr * 128 + (am >> 2) * 64 + (am & 3) * 16 + crow0 + j;
        int orow = ((r >> tcShift) << 10) + t0 + (r & tcMask);
        if (BF16OUT)
          ((unsigned short*)Cv)[(size_t)orow * N + col] = f2bf(acc[am][an][j]);
        else
          ((float*)Cv)[(size_t)orow * N + col] = acc[am][an][j];
      }
    }
}

// ---------------------------------------------------------------------------
// WKV segmented scan (segment = TS steps), stabilized (aa,bb,pp) form.
// k,v,r all bf16 now.
// ---------------------------------------------------------------------------
__global__ void wkv_part(const float* __restrict__ time_decay,
                         const unsigned short* __restrict__ k,
                         const unsigned short* __restrict__ v,
                         float* __restrict__ paA, float* __restrict__ paB,
                         float* __restrict__ paP, int Tc) {
  int idx = blockIdx.x * blockDim.x + threadIdx.x;
  int c = idx & (CC - 1);
  int b = (idx >> 11) & (BB - 1);
  int s = idx >> 15;
  float w = -__expf(time_decay[c]);
  float aa = 0.f, bb = 0.f, pp = -1e38f;
  size_t base = ((size_t)b * Tc + s * TS) * CC + c;
  for (int t = 0; t < TS; ++t) {
    size_t off = base + (size_t)t * CC;
    float kt = bf2f(k[off]), vt = bf2f(v[off]);
    float ww2 = pp + w;
    float p2 = fmaxf(ww2, kt);
    float e1 = __expf(ww2 - p2), e2 = __expf(kt - p2);
    aa = e1 * aa + e2 * vt;
    bb = e1 * bb + e2;
    pp = p2;
  }
  paA[idx] = aa; paB[idx] = bb; paP[idx] = pp;
}

__global__ void wkv_comb(const float* __restrict__ time_decay,
                         const float* __restrict__ paA,
                         const float* __restrict__ paB,
                         const float* __restrict__ paP,
                         float* __restrict__ inA, float* __restrict__ inB,
                         float* __restrict__ inP,
                         float* __restrict__ state, int S, int t0) {
  int idx = blockIdx.x * blockDim.x + threadIdx.x;  // [0, BB*CC)
  int c = idx & (CC - 1);
  float w = -__expf(time_decay[c]);
  float wTs = w * (float)TS;
  float A, Bv, P;
  if (t0 == 0) { A = 0.f; Bv = 0.f; P = -1e38f; }
  else { A = state[idx]; Bv = state[32768 + idx]; P = state[65536 + idx]; }
  for (int s = 0; s < S; ++s) {
    size_t o = (size_t)s * 32768 + idx;
    inA[o] = A; inB[o] = Bv; inP[o] = P;
    float Pd = P + wTs;
    float Ps = paP[o];
    float Pn = fmaxf(Pd, Ps);
    float e1 = __expf(Pd - Pn), e2 = __expf(Ps - Pn);
    A = e1 * A + e2 * paA[o];
    Bv = e1 * Bv + e2 * paB[o];
    P = Pn;
  }
  state[idx] = A; state[32768 + idx] = Bv; state[65536 + idx] = P;
}

__global__ void wkv_out(const float* __restrict__ time_decay,
                        const float* __restrict__ time_first,
                        const unsigned short* __restrict__ k,
                        const unsigned short* __restrict__ v,
                        const unsigned short* __restrict__ r,
                        unsigned short* __restrict__ rwkv,
                        const float* __restrict__ inA,
                        const float* __restrict__ inB,
                        const float* __restrict__ inP, int Tc) {
  int idx = blockIdx.x * blockDim.x + threadIdx.x;
  int c = idx & (CC - 1);
  int b = (idx >> 11) & (BB - 1);
  int s = idx >> 15;
  float w = -__expf(time_decay[c]);
  float u = time_first[c];
  float aa = inA[idx], bb = inB[idx], pp = inP[idx];
  size_t base = ((size_t)b * Tc + s * TS) * CC + c;
  for (int t = 0; t < TS; ++t) {
    size_t off = base + (size_t)t * CC;
    float kt = bf2f(k[off]), vt = bf2f(v[off]);
    float ww = u + kt;
    float p = fmaxf(pp, ww);
    float e1 = __expf(pp - p), e2 = __expf(ww - p);
    float y = (e1 * aa + e2 * vt) / (e1 * bb + e2);
    float rr = bf2f(r[off]);
    float sr = 1.f / (1.f + __expf(-rr));
    rwkv[off] = f2bf(sr * y);
    float ww2 = pp + w;
    float p2 = fmaxf(ww2, kt);
    float e1b = __expf(ww2 - p2), e2b = __expf(kt - p2);
    aa = e1b * aa + e2b * vt;
    bb = e1b * bb + e2b;
    pp = p2;
  }
}

extern "C" void kernel_launch(void* const* d_in, const int* in_sizes, int n_in,
                              void* d_out, int out_size, void* d_ws,
                              size_t ws_size, hipStream_t stream) {
  const float* x          = (const float*)d_in[0];
  const float* time_decay = (const float*)d_in[1];
  const float* time_first = (const float*)d_in[2];
  const float* tmk        = (const float*)d_in[3];
  const float* tmv        = (const float*)d_in[4];
  const float* tmr        = (const float*)d_in[5];
  const float* key_w      = (const float*)d_in[6];
  const float* value_w    = (const float*)d_in[7];
  const float* rec_w      = (const float*)d_in[8];
  const float* out_w      = (const float*)d_in[9];
  float* out = (float*)d_out;

  const size_t WW = (size_t)CC * CC;
  const size_t wtBytes = 4 * WW * 2;               // 32 MB
  const size_t stBytes = 3 * (size_t)BB * CC * 4;  // 384 KB

  // per-chunk = BB*Tc*CC * (xk2+xv2+xr2+rbuf2+kbuf2+vbuf2) = 12 B/elem
  int Tc = 1024;
  while (Tc > 32) {
    size_t chunkBytes = (size_t)BB * Tc * CC * 12;
    if (wtBytes + stBytes + chunkBytes + 1024 <= ws_size) break;
    Tc >>= 1;
  }
  const int Mc = BB * Tc;
  const size_t NC = (size_t)Mc * CC;
  const int S = Tc / TS;

  char* p = (char*)d_ws;
  unsigned short* wk  = (unsigned short*)p; p += WW * 2;
  unsigned short* wv  = (unsigned short*)p; p += WW * 2;
  unsigned short* wrr = (unsigned short*)p; p += WW * 2;
  unsigned short* wo  = (unsigned short*)p; p += WW * 2;
  float* state        = (float*)p;          p += stBytes;
  unsigned short* kbuf= (unsigned short*)p; p += NC * 2;
  unsigned short* vbuf= (unsigned short*)p; p += NC * 2;
  unsigned short* xk  = (unsigned short*)p; p += NC * 2;  // aliased: rwkv
  unsigned short* xv  = (unsigned short*)p; p += NC * 2;  // aliased: scan bufs
  unsigned short* xr  = (unsigned short*)p; p += NC * 2;
  unsigned short* rbuf= (unsigned short*)p; p += NC * 2;
  unsigned short* rwkv = xk;

  const size_t SBt = (size_t)S * 32768;
  float* paA = (float*)xv;
  float* paB = paA + SBt;
  float* paP = paB + SBt;
  float* inA = paP + SBt;
  float* inB = inA + SBt;
  float* inP = inB + SBt;

  f2bf_all<<<2048, 256, 0, stream>>>(key_w, value_w, rec_w, out_w,
                                     wk, wv, wrr, wo, (int)(WW / 4));

  int tcShift = 0;
  while ((1 << tcShift) < Tc) ++tcShift;

  const int nwg = (Mc / 256) * (CC / 256);
  int mixBlocks = (Mc * (CC / 4) + 255) / 256;
  if (mixBlocks > 4096) mixBlocks = 4096;

  for (int t0 = 0; t0 < TT; t0 += Tc) {
    mix_kernel<<<mixBlocks, 256, 0, stream>>>(x, tmk, tmv, tmr, xk, xv, xr,
                                              t0, Tc);
    gemm256<true><<<nwg, 512, 0, stream>>>(xk, wk, kbuf, Mc, CC, CC, 10, 0);
    gemm256<true><<<nwg, 512, 0, stream>>>(xv, wv, vbuf, Mc, CC, CC, 10, 0);
    wkv_part<<<S * 128, 256, 0, stream>>>(time_decay, kbuf, vbuf,
                                          paA, paB, paP, Tc);
    gemm256<true><<<nwg, 512, 0, stream>>>(xr, wrr, rbuf, Mc, CC, CC, 10, 0);
    wkv_comb<<<128, 256, 0, stream>>>(time_decay, paA, paB, paP,
                                      inA, inB, inP, state, S, t0);
    wkv_out<<<S * 128, 256, 0, stream>>>(time_decay, time_first, kbuf, vbuf,
                                         rbuf, rwkv, inA, inB, inP, Tc);
    gemm256<false><<<nwg, 512, 0, stream>>>(rwkv, wo, out, Mc, CC, CC,
                                            tcShift, t0);
  }
}

// Round 6
// 715.447 us; speedup vs baseline: 2.2860x; 1.0177x over previous
//
#include <hip/hip_runtime.h>
#include <hip/hip_bf16.h>

#define BB 16
#define TT 1024
#define CC 2048
#define TS 32   // wkv scan segment length

typedef __attribute__((ext_vector_type(4))) float f32x4;
typedef __attribute__((ext_vector_type(8))) short bf16x8;

__device__ __forceinline__ unsigned short f2bf(float f) {
  union { float f; unsigned u; } x; x.f = f;
  unsigned r = x.u + 0x7fffu + ((x.u >> 16) & 1u);
  return (unsigned short)(r >> 16);
}
__device__ __forceinline__ float bf2f(unsigned short u) {
  union { unsigned u; float f; } x; x.u = ((unsigned)u) << 16;
  return x.f;
}

__device__ __forceinline__ ushort4 mix4(float4 a, float4 b, float4 m) {
  ushort4 o;
  o.x = f2bf(a.x * m.x + b.x * (1.f - m.x));
  o.y = f2bf(a.y * m.y + b.y * (1.f - m.y));
  o.z = f2bf(a.z * m.z + b.z * (1.f - m.z));
  o.w = f2bf(a.w * m.w + b.w * (1.f - m.w));
  return o;
}

__global__ void f2bf_all(const float* __restrict__ w0, const float* __restrict__ w1,
                         const float* __restrict__ w2, const float* __restrict__ w3,
                         unsigned short* __restrict__ o0, unsigned short* __restrict__ o1,
                         unsigned short* __restrict__ o2, unsigned short* __restrict__ o3,
                         int n4each) {
  const float* ws[4] = {w0, w1, w2, w3};
  unsigned short* os[4] = {o0, o1, o2, o3};
  int total = 4 * n4each;
  for (int i = blockIdx.x * blockDim.x + threadIdx.x; i < total;
       i += gridDim.x * blockDim.x) {
    int seg = i / n4each, j = i - seg * n4each;
    float4 v = ((const float4*)ws[seg])[j];
    ushort4 o;
    o.x = f2bf(v.x); o.y = f2bf(v.y); o.z = f2bf(v.z); o.w = f2bf(v.w);
    ((ushort4*)os[seg])[j] = o;
  }
}

__global__ void mix_kernel(const float* __restrict__ x,
                           const float* __restrict__ tmk,
                           const float* __restrict__ tmv,
                           const float* __restrict__ tmr,
                           unsigned short* __restrict__ xk,
                           unsigned short* __restrict__ xv,
                           unsigned short* __restrict__ xr,
                           int t0, int Tc) {
  const int C4 = CC / 4;
  const int total = BB * Tc * C4;
  for (int g = blockIdx.x * blockDim.x + threadIdx.x; g < total;
       g += gridDim.x * blockDim.x) {
    int cg = g % C4;
    int lrow = g / C4;
    int tl = lrow % Tc;
    int b = lrow / Tc;
    int t = t0 + tl;
    size_t gidx = (size_t)(b * TT + t) * C4 + cg;
    float4 xc = ((const float4*)x)[gidx];
    float4 xp = make_float4(0.f, 0.f, 0.f, 0.f);
    if (t > 0) xp = ((const float4*)x)[gidx - C4];
    ((ushort4*)xk)[g] = mix4(xc, xp, ((const float4*)tmk)[cg]);
    ((ushort4*)xv)[g] = mix4(xc, xp, ((const float4*)tmv)[cg]);
    ((ushort4*)xr)[g] = mix4(xc, xp, ((const float4*)tmr)[cg]);
  }
}

// ---------------------------------------------------------------------------
// 256x256 GEMM, BK=64, 8 waves (2x4), 8-phase schedule over 2 K-tiles/iter:
// per phase {ds_read quadrant subtile ; stage 1 half-tile (2 gloads) ;
// barrier ; setprio+16 MFMA ; [vmcnt(4) at phase 3/7 ends] ; barrier}.
// Halves defined by consumption: A-half h = rows {h*64+0..63, 128+h*64+..};
// B-half h = rows wc*64+h*32+0..31 (per-lane source row permutation, linear
// LDS dest). st_16x32-style XOR swizzle both-sides. XCD-bijective swizzle.
// C[orow,N] = A[M,K]*B[N,K]^T ; orow = (r>>tcShift)<<10 + t0 + (r&mask).
// ---------------------------------------------------------------------------
template<bool BF16OUT>
__global__ __launch_bounds__(512, 2)
void gemm256(const unsigned short* __restrict__ A,
             const unsigned short* __restrict__ B,
             void* __restrict__ Cv, int M, int N, int K,
             int tcShift, int t0) {
  __shared__ __align__(1024) unsigned char lds[131072];
  const int tid = threadIdx.x;
  const int lane = tid & 63;
  const int wid = tid >> 6;
  const int wr = wid >> 2;   // 0..1
  const int wc = wid & 3;    // 0..3

  const int nwg = gridDim.x;
  const int cpx = nwg >> 3;
  const int bid = blockIdx.x;
  const int wg = (bid & 7) * cpx + (bid >> 3);
  const int bcolN = N >> 8;
  const int brow = wg / bcolN;
  const int bcol = wg % bcolN;

  const unsigned short* Ag = A + (size_t)(brow * 256) * K;
  const unsigned short* Bg = B + (size_t)(bcol * 256) * K;

  const int srow = tid >> 3;                                   // 0..63
  const int scolE = ((((tid & 7) * 16) ^ ((srow & 7) << 4)) >> 1);
  const int ldsWave = wid * 1024;
  const int rowB0 = ((srow >> 5) << 6) + (srow & 31);

  const int frow = lane & 15;
  const int fhi = (lane >> 4) << 4;
  const int fsw = (frow & 7) << 4;

// A slot(par,h) @ par*32768 + h*16384 ; B slot @ 65536 + same. 2 gloads/half.
#define STA(par, h, g, kk)                                                     \
  __builtin_amdgcn_global_load_lds(                                            \
      (const __attribute__((address_space(1))) void*)(                         \
          Ag + (size_t)(srow + (h) * 64 + (g) * 128) * K + (kk) + scolE),      \
      (__attribute__((address_space(3))) void*)(                               \
          lds + (par) * 32768 + (h) * 16384 + (g) * 8192 + ldsWave), 16, 0, 0)
#define STB(par, h, g, kk)                                                     \
  __builtin_amdgcn_global_load_lds(                                            \
      (const __attribute__((address_space(1))) void*)(                         \
          Bg + (size_t)(rowB0 + (h) * 32 + (g) * 128) * K + (kk) + scolE),     \
      (__attribute__((address_space(3))) void*)(                               \
          lds + 65536 + (par) * 32768 + (h) * 16384 + (g) * 8192 + ldsWave),   \
      16, 0, 0)

#define RD_A(par, h)                                                           \
  do { _Pragma("unroll") for (int m = 0; m < 4; ++m)                           \
       _Pragma("unroll") for (int kk = 0; kk < 2; ++kk)                        \
         af[m * 2 + kk] = *(const bf16x8*)(lds + (par) * 32768 +               \
             (h) * 16384 + (wr * 64 + m * 16 + frow) * 128 +                   \
             (((kk << 6) + fhi) ^ fsw));                                       \
  } while (0)
#define RD_B(par, h)                                                           \
  do { _Pragma("unroll") for (int n = 0; n < 2; ++n)                           \
       _Pragma("unroll") for (int kk = 0; kk < 2; ++kk)                        \
         bf[n * 2 + kk] = *(const bf16x8*)(lds + 65536 + (par) * 32768 +       \
             (h) * 16384 + (wc * 32 + n * 16 + frow) * 128 +                   \
             (((kk << 6) + fhi) ^ fsw));                                       \
  } while (0)

#define MFMA_Q(AM, AN)                                                         \
  do { __builtin_amdgcn_s_setprio(1);                                          \
       _Pragma("unroll") for (int m = 0; m < 4; ++m)                           \
       _Pragma("unroll") for (int n = 0; n < 2; ++n)                           \
       _Pragma("unroll") for (int kk = 0; kk < 2; ++kk)                        \
         acc[(AM) + m][(AN) + n] = __builtin_amdgcn_mfma_f32_16x16x32_bf16(    \
             af[m * 2 + kk], bf[n * 2 + kk], acc[(AM) + m][(AN) + n], 0, 0, 0);\
       __builtin_amdgcn_s_setprio(0); } while (0)

#define BAR __builtin_amdgcn_s_barrier()
#define VMC4 asm volatile("s_waitcnt vmcnt(4)" ::: "memory")
#define VMC0 asm volatile("s_waitcnt vmcnt(0)" ::: "memory")

  const int NI = K >> 7;   // iterations; 2 K-tiles each

  // Prologue: tile0 (8 loads, oldest) + tile1's Ah0,Bh1 (4 loads, newest).
  STA(0, 0, 0, 0); STA(0, 0, 1, 0);
  STA(0, 1, 0, 0); STA(0, 1, 1, 0);
  STB(0, 0, 0, 0); STB(0, 0, 1, 0);
  STB(0, 1, 0, 0); STB(0, 1, 1, 0);
  STA(1, 0, 0, 64); STA(1, 0, 1, 64);
  STB(1, 1, 0, 64); STB(1, 1, 1, 64);
  VMC4;           // tile0 fully drained; tile1 halves in flight
  BAR;

  f32x4 acc[8][4] = {};
  bf16x8 af[8], bf[4];

  for (int i = 0; i < NI; ++i) {
    const int k1 = (2 * i + 1) << 6;
    const int k2 = (2 * i + 2) << 6;
    const int k3 = (2 * i + 3) << 6;
    const bool st = (i + 1 < NI);

    // ph0: T0 quadrant (mh0,nh0); stage B-h0[T1]
    RD_A(0, 0); RD_B(0, 0);
    STB(1, 0, 0, k1); STB(1, 0, 1, k1);
    BAR; MFMA_Q(0, 0); BAR;

    // ph1: (mh0,nh1); stage A-h1[T1]
    RD_B(0, 1);
    STA(1, 1, 0, k1); STA(1, 1, 1, k1);
    BAR; MFMA_Q(0, 2); BAR;

    // ph2: (mh1,nh1); stage A-h0[T0+2]
    RD_A(0, 1);
    if (st) { STA(0, 0, 0, k2); STA(0, 0, 1, k2); }
    BAR; MFMA_Q(4, 2); BAR;

    // ph3: (mh1,nh0) re-read B-h0; stage B-h1[T0+2]; boundary drain (T1 valid)
    RD_B(0, 0);
    if (st) { STB(0, 1, 0, k2); STB(0, 1, 1, k2); }
    BAR; MFMA_Q(4, 0);
    if (st) { VMC4; } else { VMC0; }
    BAR;

    // ph4: T1 quadrant (mh0,nh0); stage A-h1[T0+2]
    RD_A(1, 0); RD_B(1, 0);
    if (st) { STA(0, 1, 0, k2); STA(0, 1, 1, k2); }
    BAR; MFMA_Q(0, 0); BAR;

    // ph5: (mh0,nh1); stage B-h0[T0+2]
    RD_B(1, 1);
    if (st) { STB(0, 0, 0, k2); STB(0, 0, 1, k2); }
    BAR; MFMA_Q(0, 2); BAR;

    // ph6: (mh1,nh1); stage A-h0[T1+2]
    RD_A(1, 1);
    if (st) { STA(1, 0, 0, k3); STA(1, 0, 1, k3); }
    BAR; MFMA_Q(4, 2); BAR;

    // ph7: (mh1,nh0) re-read B-h0; stage B-h1[T1+2]; boundary drain (T0+2 valid)
    RD_B(1, 0);
    if (st) { STB(1, 1, 0, k3); STB(1, 1, 1, k3); }
    BAR; MFMA_Q(4, 0);
    if (st) { VMC4; }
    BAR;
  }
#undef STA
#undef STB
#undef RD_A
#undef RD_B
#undef MFMA_Q
#undef BAR
#undef VMC4
#undef VMC0

  const int crow0 = (lane >> 4) << 2;
  const int ccol = lane & 15;
  const int tcMask = (1 << tcShift) - 1;
#pragma unroll
  for (int am = 0; am < 8; ++am)
#pragma unroll
    for (int an = 0; an < 4; ++an) {
      const int col = bcol * 256 + wc * 64 + (an >> 1) * 32 + (an & 1) * 16 + ccol;
#pragma unroll
      for (int j = 0; j < 4; ++j) {
        int r = brow * 256 + wr * 128 + (am >> 2) * 64 + (am & 3) * 16 + crow0 + j;
        int orow = ((r >> tcShift) << 10) + t0 + (r & tcMask);
        if (BF16OUT)
          ((unsigned short*)Cv)[(size_t)orow * N + col] = f2bf(acc[am][an][j]);
        else
          ((float*)Cv)[(size_t)orow * N + col] = acc[am][an][j];
      }
    }
}

// ---------------------------------------------------------------------------
// WKV segmented scan (segment = TS steps), stabilized (aa,bb,pp) form.
// ---------------------------------------------------------------------------
__global__ void wkv_part(const float* __restrict__ time_decay,
                         const unsigned short* __restrict__ k,
                         const unsigned short* __restrict__ v,
                         float* __restrict__ paA, float* __restrict__ paB,
                         float* __restrict__ paP, int Tc) {
  int idx = blockIdx.x * blockDim.x + threadIdx.x;
  int c = idx & (CC - 1);
  int b = (idx >> 11) & (BB - 1);
  int s = idx >> 15;
  float w = -__expf(time_decay[c]);
  float aa = 0.f, bb = 0.f, pp = -1e38f;
  size_t base = ((size_t)b * Tc + s * TS) * CC + c;
  for (int t = 0; t < TS; ++t) {
    size_t off = base + (size_t)t * CC;
    float kt = bf2f(k[off]), vt = bf2f(v[off]);
    float ww2 = pp + w;
    float p2 = fmaxf(ww2, kt);
    float e1 = __expf(ww2 - p2), e2 = __expf(kt - p2);
    aa = e1 * aa + e2 * vt;
    bb = e1 * bb + e2;
    pp = p2;
  }
  paA[idx] = aa; paB[idx] = bb; paP[idx] = pp;
}

__global__ void wkv_comb(const float* __restrict__ time_decay,
                         const float* __restrict__ paA,
                         const float* __restrict__ paB,
                         const float* __restrict__ paP,
                         float* __restrict__ inA, float* __restrict__ inB,
                         float* __restrict__ inP,
                         float* __restrict__ state, int S, int t0) {
  int idx = blockIdx.x * blockDim.x + threadIdx.x;  // [0, BB*CC)
  int c = idx & (CC - 1);
  float w = -__expf(time_decay[c]);
  float wTs = w * (float)TS;
  float A, Bv, P;
  if (t0 == 0) { A = 0.f; Bv = 0.f; P = -1e38f; }
  else { A = state[idx]; Bv = state[32768 + idx]; P = state[65536 + idx]; }
  for (int s = 0; s < S; ++s) {
    size_t o = (size_t)s * 32768 + idx;
    inA[o] = A; inB[o] = Bv; inP[o] = P;
    float Pd = P + wTs;
    float Ps = paP[o];
    float Pn = fmaxf(Pd, Ps);
    float e1 = __expf(Pd - Pn), e2 = __expf(Ps - Pn);
    A = e1 * A + e2 * paA[o];
    Bv = e1 * Bv + e2 * paB[o];
    P = Pn;
  }
  state[idx] = A; state[32768 + idx] = Bv; state[65536 + idx] = P;
}

__global__ void wkv_out(const float* __restrict__ time_decay,
                        const float* __restrict__ time_first,
                        const unsigned short* __restrict__ k,
                        const unsigned short* __restrict__ v,
                        const unsigned short* __restrict__ r,
                        unsigned short* __restrict__ rwkv,
                        const float* __restrict__ inA,
                        const float* __restrict__ inB,
                        const float* __restrict__ inP, int Tc) {
  int idx = blockIdx.x * blockDim.x + threadIdx.x;
  int c = idx & (CC - 1);
  int b = (idx >> 11) & (BB - 1);
  int s = idx >> 15;
  float w = -__expf(time_decay[c]);
  float u = time_first[c];
  float aa = inA[idx], bb = inB[idx], pp = inP[idx];
  size_t base = ((size_t)b * Tc + s * TS) * CC + c;
  for (int t = 0; t < TS; ++t) {
    size_t off = base + (size_t)t * CC;
    float kt = bf2f(k[off]), vt = bf2f(v[off]);
    float ww = u + kt;
    float p = fmaxf(pp, ww);
    float e1 = __expf(pp - p), e2 = __expf(ww - p);
    float y = (e1 * aa + e2 * vt) / (e1 * bb + e2);
    float rr = bf2f(r[off]);
    float sr = 1.f / (1.f + __expf(-rr));
    rwkv[off] = f2bf(sr * y);
    float ww2 = pp + w;
    float p2 = fmaxf(ww2, kt);
    float e1b = __expf(ww2 - p2), e2b = __expf(kt - p2);
    aa = e1b * aa + e2b * vt;
    bb = e1b * bb + e2b;
    pp = p2;
  }
}

extern "C" void kernel_launch(void* const* d_in, const int* in_sizes, int n_in,
                              void* d_out, int out_size, void* d_ws,
                              size_t ws_size, hipStream_t stream) {
  const float* x          = (const float*)d_in[0];
  const float* time_decay = (const float*)d_in[1];
  const float* time_first = (const float*)d_in[2];
  const float* tmk        = (const float*)d_in[3];
  const float* tmv        = (const float*)d_in[4];
  const float* tmr        = (const float*)d_in[5];
  const float* key_w      = (const float*)d_in[6];
  const float* value_w    = (const float*)d_in[7];
  const float* rec_w      = (const float*)d_in[8];
  const float* out_w      = (const float*)d_in[9];
  float* out = (float*)d_out;

  const size_t WW = (size_t)CC * CC;
  const size_t wtBytes = 4 * WW * 2;               // 32 MB
  const size_t stBytes = 3 * (size_t)BB * CC * 4;  // 384 KB

  // per-chunk = BB*Tc*CC * (xk2+xv2+xr2+rbuf2+kbuf2+vbuf2) = 12 B/elem
  int Tc = 1024;
  while (Tc > 32) {
    size_t chunkBytes = (size_t)BB * Tc * CC * 12;
    if (wtBytes + stBytes + chunkBytes + 1024 <= ws_size) break;
    Tc >>= 1;
  }
  const int Mc = BB * Tc;
  const size_t NC = (size_t)Mc * CC;
  const int S = Tc / TS;

  char* p = (char*)d_ws;
  unsigned short* wk  = (unsigned short*)p; p += WW * 2;
  unsigned short* wv  = (unsigned short*)p; p += WW * 2;
  unsigned short* wrr = (unsigned short*)p; p += WW * 2;
  unsigned short* wo  = (unsigned short*)p; p += WW * 2;
  float* state        = (float*)p;          p += stBytes;
  unsigned short* kbuf= (unsigned short*)p; p += NC * 2;
  unsigned short* vbuf= (unsigned short*)p; p += NC * 2;
  unsigned short* xk  = (unsigned short*)p; p += NC * 2;  // aliased: rwkv
  unsigned short* xv  = (unsigned short*)p; p += NC * 2;  // aliased: scan bufs
  unsigned short* xr  = (unsigned short*)p; p += NC * 2;
  unsigned short* rbuf= (unsigned short*)p; p += NC * 2;
  unsigned short* rwkv = xk;

  const size_t SBt = (size_t)S * 32768;
  float* paA = (float*)xv;
  float* paB = paA + SBt;
  float* paP = paB + SBt;
  float* inA = paP + SBt;
  float* inB = inA + SBt;
  float* inP = inB + SBt;

  f2bf_all<<<2048, 256, 0, stream>>>(key_w, value_w, rec_w, out_w,
                                     wk, wv, wrr, wo, (int)(WW / 4));

  int tcShift = 0;
  while ((1 << tcShift) < Tc) ++tcShift;

  const int nwg = (Mc / 256) * (CC / 256);
  int mixBlocks = (Mc * (CC / 4) + 255) / 256;
  if (mixBlocks > 4096) mixBlocks = 4096;

  for (int t0 = 0; t0 < TT; t0 += Tc) {
    mix_kernel<<<mixBlocks, 256, 0, stream>>>(x, tmk, tmv, tmr, xk, xv, xr,
                                              t0, Tc);
    gemm256<true><<<nwg, 512, 0, stream>>>(xk, wk, kbuf, Mc, CC, CC, 10, 0);
    gemm256<true><<<nwg, 512, 0, stream>>>(xv, wv, vbuf, Mc, CC, CC, 10, 0);
    wkv_part<<<S * 128, 256, 0, stream>>>(time_decay, kbuf, vbuf,
                                          paA, paB, paP, Tc);
    gemm256<true><<<nwg, 512, 0, stream>>>(xr, wrr, rbuf, Mc, CC, CC, 10, 0);
    wkv_comb<<<128, 256, 0, stream>>>(time_decay, paA, paB, paP,
                                      inA, inB, inP, state, S, t0);
    wkv_out<<<S * 128, 256, 0, stream>>>(time_decay, time_first, kbuf, vbuf,
                                         rbuf, rwkv, inA, inB, inP, Tc);
    gemm256<false><<<nwg, 512, 0, stream>>>(rwkv, wo, out, Mc, CC, CC,
                                            tcShift, t0);
  }
}